// Round 8
// baseline (150.586 us; speedup 1.0000x reference)
//
#include <hip/hip_runtime.h>
#include <math.h>

// Problem constants
#define CC   128         // channels
#define NL   16384       // N * H * W = 4*64*64
#define LHW  4096        // H*W
#define OMP  112         // padded om row stride: 4 groups x (27+1 pad) floats
#define HH   64
#define WW   64

typedef __attribute__((ext_vector_type(8))) short short8;
typedef __attribute__((ext_vector_type(4))) float f32x4;

__device__ __forceinline__ unsigned short f2bf(float f) {
    union { float f; unsigned u; } v; v.f = f;
    unsigned r = v.u + 0x7fff + ((v.u >> 16) & 1);   // RNE
    return (unsigned short)(r >> 16);
}
__device__ __forceinline__ float bf2f(unsigned short u) {
    union { unsigned u; float f; } v; v.u = ((unsigned)u) << 16;
    return v.f;
}

// ---------------------------------------------------------------------------
// Weight prep + stats zero + x -> xT (bf16 NHWC).
// Blocks 0..247: Wcomb[240][128] (Wv^T | Wom^T pad->112), WoT, Wcb, stats=0.
// Blocks 248..503: xT[nl][128] = f2bf(x NCHW)  (bit-identical to vom<0>'s
// former in-kernel transpose; lets vom<0> A-stage be a pure vector copy).
// ---------------------------------------------------------------------------
__global__ __launch_bounds__(256) void prep_kernel(
    const float* __restrict__ Wv, const float* __restrict__ Wom,
    const float* __restrict__ Wo, const float* __restrict__ Wc,
    const float* __restrict__ x,
    unsigned short* __restrict__ Wcomb, unsigned short* __restrict__ WoT,
    unsigned short* __restrict__ Wcb, unsigned short* __restrict__ xT,
    float* __restrict__ stats)
{
    int tid = threadIdx.x;
    int b = blockIdx.x;
    if (b < 248) {
        if (b == 0) {                        // zero 512 stats floats
            stats[tid] = 0.0f;
            stats[256 + tid] = 0.0f;
        }
        int i = b * 256 + tid;               // 63488 total
        if (i < 16384) {
            int n = i >> 7, k = i & 127;
            Wcomb[i] = f2bf(Wv[k * CC + n]);
        } else if (i < 30720) {
            int j = i - 16384; int n = j >> 7, k = j & 127;   // n in 0..111
            Wcomb[16384 + j] = (n < 108) ? f2bf(Wom[k * 108 + n]) : (unsigned short)0;
        } else if (i < 47104) {
            int j = i - 30720; int n = j >> 7, k = j & 127;
            WoT[j] = f2bf(Wo[k * CC + n]);
        } else if (i < 63488) {
            int j = i - 47104;
            Wcb[j] = f2bf(Wc[j]);
        }
    } else {
        __shared__ alignas(16) unsigned short As[64 * 136];
        int block_m = (b - 248) * 64;
        int n   = block_m >> 12;
        int hw0 = block_m & 4095;
#pragma unroll
        for (int i = 0; i < 8; i++) {
            int id = tid + i * 256;          // 0..2047
            int c  = id >> 4, j4 = id & 15;
            float4 v = *(const float4*)(x + (((size_t)(n * CC + c)) << 12) + hw0 + j4 * 4);
            unsigned p01 = (unsigned)f2bf(v.x) | ((unsigned)f2bf(v.y) << 16);
            unsigned p23 = (unsigned)f2bf(v.z) | ((unsigned)f2bf(v.w) << 16);
            // rows j4*4..j4*4+3, column c (scalar writes; transpose)
            As[(j4 * 4 + 0) * 136 + c] = (unsigned short)(p01 & 0xffff);
            As[(j4 * 4 + 1) * 136 + c] = (unsigned short)(p01 >> 16);
            As[(j4 * 4 + 2) * 136 + c] = (unsigned short)(p23 & 0xffff);
            As[(j4 * 4 + 3) * 136 + c] = (unsigned short)(p23 >> 16);
        }
        __syncthreads();
#pragma unroll
        for (int i = 0; i < 4; i++) {
            int id = tid + i * 256;          // 0..1023
            int r = id >> 4, kc = id & 15;
            *(float4*)(xT + (size_t)(block_m + r) * CC + kc * 8) =
                *(const float4*)(&As[r * 136 + kc * 8]);
        }
    }
}

// ---------------------------------------------------------------------------
// Fused value+om GEMM: [M=16384 x N=240 x K=128].
// IN_MODE 0: A = xT (bf16 NHWC, prep-transposed) -> pure vector-copy staging.
// IN_MODE 1: A = bn_relu(ybuf) (NHWC), bn applied in staging (b32-packed).
// Outputs:
//   val bf16 in g-major layout [n][g][hw][32] (+bv)
//   omb fp32 in layout [nl][4][28] (+bom, e<27)
// 4 waves; wave w computes rows w*16..w*16+15 x all 240 cols (15 frags).
// MFMA chains identical to the verified baseline.
// ---------------------------------------------------------------------------
template<int IN_MODE>
__global__ __launch_bounds__(256) void gemm_vom_kernel(
    const void* __restrict__ Ain_, const unsigned short* __restrict__ Wcomb,
    const float* __restrict__ bv, const float* __restrict__ bom,
    const float* __restrict__ stats, const float* __restrict__ gamma,
    const float* __restrict__ beta,
    unsigned short* __restrict__ val, float* __restrict__ omb)
{
    __shared__ unsigned short As[64 * 136];
    __shared__ unsigned short Bs[240 * 136];
    __shared__ float bnsc[128], bnsh[128];

    int tid = threadIdx.x;
    int block_m = blockIdx.x * 64;

    if (IN_MODE == 1 && tid < 128) {
        const float inv = 1.0f / 16384.0f;
        float mean = stats[tid] * inv;
        float var  = stats[128 + tid] * inv - mean * mean;
        float sc   = rsqrtf(var + 1e-5f) * gamma[tid];
        bnsc[tid] = sc;
        bnsh[tid] = beta[tid] - mean * sc;
    }

    // stage B: 240 rows x 128 bf16 = 3840 chunks of 8  (15 x 256, exact)
#pragma unroll
    for (int i = 0; i < 15; i++) {
        int id = tid + i * 256;
        int r = id >> 4, kc = id & 15;
        float4 v = *(const float4*)(Wcomb + (size_t)r * CC + kc * 8);
        *(float4*)(&Bs[r * 136 + kc * 8]) = v;
    }

    if (IN_MODE == 0) {
        // A from xT bf16 NHWC: straight vector copy (bit-identical LDS image)
        const unsigned short* xT = (const unsigned short*)Ain_;
#pragma unroll
        for (int i = 0; i < 4; i++) {
            int id = tid + i * 256;          // 0..1023
            int r = id >> 4, kc = id & 15;
            float4 v = *(const float4*)(xT + (size_t)(block_m + r) * CC + kc * 8);
            *(float4*)(&As[r * 136 + kc * 8]) = v;
        }
    } else {
        const float* Ain = (const float*)Ain_;
        __syncthreads();                     // bnsc/bnsh ready
#pragma unroll
        for (int i = 0; i < 8; i++) {
            int id = tid + i * 256;          // 0..2047
            int r  = id >> 5, c4 = id & 31;
            float4 v = *(const float4*)(Ain + (size_t)(block_m + r) * CC + c4 * 4);
            int c = c4 * 4;
            float a0 = fmaxf(v.x * bnsc[c + 0] + bnsh[c + 0], 0.0f);
            float a1 = fmaxf(v.y * bnsc[c + 1] + bnsh[c + 1], 0.0f);
            float a2 = fmaxf(v.z * bnsc[c + 2] + bnsh[c + 2], 0.0f);
            float a3 = fmaxf(v.w * bnsc[c + 3] + bnsh[c + 3], 0.0f);
            unsigned p0 = (unsigned)f2bf(a0) | ((unsigned)f2bf(a1) << 16);
            unsigned p1 = (unsigned)f2bf(a2) | ((unsigned)f2bf(a3) << 16);
            *(unsigned*)(&As[r * 136 + c])     = p0;   // (136r+c)*2 % 4 == 0
            *(unsigned*)(&As[r * 136 + c + 2]) = p1;
        }
    }
    __syncthreads();

    int w  = tid >> 6;
    int l  = tid & 63;
    int lr = l & 15, lk = l >> 4;

    f32x4 acc[15];
#pragma unroll
    for (int nt = 0; nt < 15; nt++) acc[nt] = (f32x4){0.f, 0.f, 0.f, 0.f};

#pragma unroll
    for (int kk = 0; kk < 4; kk++) {
        short8 a = *(const short8*)(&As[(w * 16 + lr) * 136 + kk * 32 + lk * 8]);
#pragma unroll
        for (int nt = 0; nt < 15; nt++) {
            short8 b = *(const short8*)(&Bs[(nt * 16 + lr) * 136 + kk * 32 + lk * 8]);
            acc[nt] = __builtin_amdgcn_mfma_f32_16x16x32_bf16(a, b, acc[nt], 0, 0, 0);
        }
    }

    int row0  = block_m + w * 16 + lk * 4;
    int nimg  = block_m >> 12;               // constant per block (4096 % 64 == 0)
    int hwrow = row0 & 4095;
#pragma unroll
    for (int nt = 0; nt < 8; nt++) {
        int col = nt * 16 + lr;
        float bb = bv[col];
        int gg = col >> 5, ch = col & 31;
        unsigned short* vp = val + (((size_t)(nimg * 4 + gg)) << 17) + (size_t)hwrow * 32 + ch;
#pragma unroll
        for (int r = 0; r < 4; r++)
            vp[r * 32] = f2bf(acc[nt][r] + bb);
    }
#pragma unroll
    for (int nt = 8; nt < 15; nt++) {
        int col = (nt - 8) * 16 + lr;        // 0..111
        if (col < 108) {
            int gg = col / 27, e = col - gg * 27;
            float bb = bom[col];
#pragma unroll
            for (int r = 0; r < 4; r++)
                omb[(size_t)(row0 + r) * OMP + gg * 28 + e] = acc[nt][r] + bb;
        }
    }
}

// ---------------------------------------------------------------------------
// Deformable sampling: 4 lanes x 8 ch per (nl,g) unit.
// val in g-major layout: pixel g-slice = 64B contiguous; corner pair
// (x0,x0+1) = one 128B line. om loaded as 7 x float4 (16B-aligned 28-slice).
// Per-channel accumulation chains bit-identical to the verified baseline.
// ---------------------------------------------------------------------------
__global__ __launch_bounds__(256) void sample_kernel(
    const unsigned short* __restrict__ val, const float* __restrict__ omb,
    unsigned int* __restrict__ sbuf)
{
    int tid   = threadIdx.x;
    int gid   = blockIdx.x * 256 + tid;
    int unit  = gid >> 2;                    // 65536 units
    int lane4 = gid & 3;
    int nl = unit >> 2;
    int g  = unit & 3;
    int n  = nl >> 12;
    int hw = nl & 4095;
    int h  = hw >> 6;
    int w  = hw & 63;

    const float* omp = omb + (size_t)nl * OMP + g * 28;   // 16B aligned
    f32x4 o4[7];
#pragma unroll
    for (int i = 0; i < 7; i++) o4[i] = *(const f32x4*)(omp + i * 4);

    const unsigned short* vb = val + (((size_t)(n * 4 + g)) << 17) + lane4 * 8;

    float acc0 = 0.0f, acc1 = 0.0f, acc2 = 0.0f, acc3 = 0.0f;
    float acc4 = 0.0f, acc5 = 0.0f, acc6 = 0.0f, acc7 = 0.0f;
#pragma unroll
    for (int k = 0; k < 9; k++) {
        float ox = o4[(2 * k) >> 2][(2 * k) & 3];
        float oy = o4[(2 * k + 1) >> 2][(2 * k + 1) & 3];
        float mk = o4[(18 + k) >> 2][(18 + k) & 3];
        float ly = (float)(h + k / 3 - 1) + oy;
        float lx = (float)(w + k % 3 - 1) + ox;
        float y0f = floorf(ly), x0f = floorf(lx);
        float wy = ly - y0f, wx = lx - x0f;
        int y0 = (int)y0f, x0 = (int)x0f;

        float v0 = 0.0f, v1 = 0.0f, v2 = 0.0f, v3 = 0.0f;
        float v4 = 0.0f, v5 = 0.0f, v6 = 0.0f, v7 = 0.0f;
#pragma unroll
        for (int cy = 0; cy < 2; cy++) {
#pragma unroll
            for (int cx = 0; cx < 2; cx++) {
                int yi = y0 + cy, xi = x0 + cx;
                float wgt = (cy ? wy : 1.0f - wy) * (cx ? wx : 1.0f - wx);
                bool valid = (yi >= 0) && (yi < HH) && (xi >= 0) && (xi < WW);
                wgt = valid ? wgt : 0.0f;
                int yc = min(max(yi, 0), HH - 1);
                int xc = min(max(xi, 0), WW - 1);
                uint4 pv = *(const uint4*)(vb + (size_t)(yc * WW + xc) * 32);
                v0 += bf2f((unsigned short)(pv.x & 0xffff)) * wgt;
                v1 += bf2f((unsigned short)(pv.x >> 16)) * wgt;
                v2 += bf2f((unsigned short)(pv.y & 0xffff)) * wgt;
                v3 += bf2f((unsigned short)(pv.y >> 16)) * wgt;
                v4 += bf2f((unsigned short)(pv.z & 0xffff)) * wgt;
                v5 += bf2f((unsigned short)(pv.z >> 16)) * wgt;
                v6 += bf2f((unsigned short)(pv.w & 0xffff)) * wgt;
                v7 += bf2f((unsigned short)(pv.w >> 16)) * wgt;
            }
        }
        acc0 += mk * v0;
        acc1 += mk * v1;
        acc2 += mk * v2;
        acc3 += mk * v3;
        acc4 += mk * v4;
        acc5 += mk * v5;
        acc6 += mk * v6;
        acc7 += mk * v7;
    }
    uint4 packed;
    packed.x = (unsigned int)f2bf(acc0) | ((unsigned int)f2bf(acc1) << 16);
    packed.y = (unsigned int)f2bf(acc2) | ((unsigned int)f2bf(acc3) << 16);
    packed.z = (unsigned int)f2bf(acc4) | ((unsigned int)f2bf(acc5) << 16);
    packed.w = (unsigned int)f2bf(acc6) | ((unsigned int)f2bf(acc7) << 16);
    *(uint4*)(&sbuf[(size_t)nl * 64 + g * 16 + lane4 * 4]) = packed;
}

// ---------------------------------------------------------------------------
// Wo GEMM + fused BN-stats: ybuf = sbuf @ Wo ; stats[c] += sum, stats[128+c] += sumsq
// 2x2 wave grid, 64-row tile.
// ---------------------------------------------------------------------------
__global__ __launch_bounds__(256) void gemm_o_bn_kernel(
    const unsigned short* __restrict__ A, const unsigned short* __restrict__ Bt,
    float* __restrict__ ybuf, float* __restrict__ stats)
{
    __shared__ unsigned short As[64 * 136];
    __shared__ unsigned short Bs[128 * 136];
    __shared__ float lstat[256];

    int tid = threadIdx.x;
    int block_m = blockIdx.x * 64;
    lstat[tid] = 0.0f;

#pragma unroll
    for (int i = 0; i < 4; i++) {
        int id = tid + i * 256;
        int r = id >> 4, kc = id & 15;
        float4 v = *(const float4*)(A + (size_t)(block_m + r) * CC + kc * 8);
        *(float4*)(&As[r * 136 + kc * 8]) = v;
    }
#pragma unroll
    for (int i = 0; i < 8; i++) {
        int id = tid + i * 256;
        int r = id >> 4, kc = id & 15;
        float4 v = *(const float4*)(Bt + (size_t)r * CC + kc * 8);
        *(float4*)(&Bs[r * 136 + kc * 8]) = v;
    }
    __syncthreads();

    int w  = tid >> 6;
    int l  = tid & 63;
    int wm = w & 1, wn = w >> 1;
    int lr = l & 15, lk = l >> 4;

    f32x4 acc[2][4];
#pragma unroll
    for (int mt = 0; mt < 2; mt++)
#pragma unroll
        for (int nt = 0; nt < 4; nt++) acc[mt][nt] = (f32x4){0.f, 0.f, 0.f, 0.f};

#pragma unroll
    for (int kk = 0; kk < 4; kk++) {
        short8 a[2], b[4];
#pragma unroll
        for (int mt = 0; mt < 2; mt++)
            a[mt] = *(const short8*)(&As[(wm * 32 + mt * 16 + lr) * 136 + kk * 32 + lk * 8]);
#pragma unroll
        for (int nt = 0; nt < 4; nt++)
            b[nt] = *(const short8*)(&Bs[(wn * 64 + nt * 16 + lr) * 136 + kk * 32 + lk * 8]);
#pragma unroll
        for (int mt = 0; mt < 2; mt++)
#pragma unroll
            for (int nt = 0; nt < 4; nt++)
                acc[mt][nt] = __builtin_amdgcn_mfma_f32_16x16x32_bf16(
                    a[mt], b[nt], acc[mt][nt], 0, 0, 0);
    }

    // write + per-lane stats
#pragma unroll
    for (int nt = 0; nt < 4; nt++) {
        int col = wn * 64 + nt * 16 + lr;
        float s = 0.0f, sq = 0.0f;
#pragma unroll
        for (int mt = 0; mt < 2; mt++) {
            int row0 = block_m + wm * 32 + mt * 16 + lk * 4;
#pragma unroll
            for (int r = 0; r < 4; r++) {
                float v = acc[mt][nt][r];
                ybuf[(size_t)(row0 + r) * CC + col] = v;
                s += v;
                sq += v * v;
            }
        }
        atomicAdd(&lstat[col], s);
        atomicAdd(&lstat[128 + col], sq);
    }
    __syncthreads();
    if (tid < 128) {
        atomicAdd(&stats[tid], lstat[tid]);
        atomicAdd(&stats[128 + tid], lstat[128 + tid]);
    }
}

// ---------------------------------------------------------------------------
// Final GEMM: A = bn(ybuf) + x_residual(NCHW), B = Wc; out NCHW fp32.
// ---------------------------------------------------------------------------
__global__ __launch_bounds__(256) void gemm_final_kernel(
    const float* __restrict__ ybuf, const float* __restrict__ x,
    const unsigned short* __restrict__ Bt, const float* __restrict__ stats,
    const float* __restrict__ gamma, const float* __restrict__ beta,
    float* __restrict__ out)
{
    __shared__ unsigned short As[64 * 136];
    __shared__ unsigned short Bs[128 * 136];
    __shared__ float Xs[64 * 132];
    __shared__ float bnsc[128], bnsh[128];

    int tid = threadIdx.x;
    int block_m = blockIdx.x * 64;
    int n   = block_m >> 12;
    int hw0 = block_m & 4095;

    if (tid < 128) {
        const float inv = 1.0f / 16384.0f;
        float mean = stats[tid] * inv;
        float var  = stats[128 + tid] * inv - mean * mean;
        float sc   = rsqrtf(var + 1e-5f) * gamma[tid];
        bnsc[tid] = sc;
        bnsh[tid] = beta[tid] - mean * sc;
    }

    // stage x residual (NCHW -> LDS transpose, fp32)
#pragma unroll
    for (int i = 0; i < 8; i++) {
        int id = tid + i * 256;
        int c  = id >> 4, j4 = id & 15;
        float4 v = *(const float4*)(x + (((size_t)(n * CC + c)) << 12) + hw0 + j4 * 4);
        Xs[(j4 * 4 + 0) * 132 + c] = v.x;
        Xs[(j4 * 4 + 1) * 132 + c] = v.y;
        Xs[(j4 * 4 + 2) * 132 + c] = v.z;
        Xs[(j4 * 4 + 3) * 132 + c] = v.w;
    }
    // stage B
#pragma unroll
    for (int i = 0; i < 8; i++) {
        int id = tid + i * 256;
        int r = id >> 4, kc = id & 15;
        float4 v = *(const float4*)(Bt + (size_t)r * CC + kc * 8);
        *(float4*)(&Bs[r * 136 + kc * 8]) = v;
    }
    __syncthreads();

    // stage A = bn(ybuf) + Xs   (b32-packed LDS writes, bit-identical image)
#pragma unroll
    for (int i = 0; i < 8; i++) {
        int id = tid + i * 256;
        int r  = id >> 5, c4 = id & 31;
        float4 v = *(const float4*)(ybuf + (size_t)(block_m + r) * CC + c4 * 4);
        int c = c4 * 4;
        float a0 = v.x * bnsc[c + 0] + bnsh[c + 0] + Xs[r * 132 + c + 0];
        float a1 = v.y * bnsc[c + 1] + bnsh[c + 1] + Xs[r * 132 + c + 1];
        float a2 = v.z * bnsc[c + 2] + bnsh[c + 2] + Xs[r * 132 + c + 2];
        float a3 = v.w * bnsc[c + 3] + bnsh[c + 3] + Xs[r * 132 + c + 3];
        unsigned p0 = (unsigned)f2bf(a0) | ((unsigned)f2bf(a1) << 16);
        unsigned p1 = (unsigned)f2bf(a2) | ((unsigned)f2bf(a3) << 16);
        *(unsigned*)(&As[r * 136 + c])     = p0;
        *(unsigned*)(&As[r * 136 + c + 2]) = p1;
    }
    __syncthreads();

    int w  = tid >> 6;
    int l  = tid & 63;
    int wm = w & 1, wn = w >> 1;
    int lr = l & 15, lk = l >> 4;

    f32x4 acc[2][4];
#pragma unroll
    for (int mt = 0; mt < 2; mt++)
#pragma unroll
        for (int nt = 0; nt < 4; nt++) acc[mt][nt] = (f32x4){0.f, 0.f, 0.f, 0.f};

#pragma unroll
    for (int kk = 0; kk < 4; kk++) {
        short8 a[2], b[4];
#pragma unroll
        for (int mt = 0; mt < 2; mt++)
            a[mt] = *(const short8*)(&As[(wm * 32 + mt * 16 + lr) * 136 + kk * 32 + lk * 8]);
#pragma unroll
        for (int nt = 0; nt < 4; nt++)
            b[nt] = *(const short8*)(&Bs[(wn * 64 + nt * 16 + lr) * 136 + kk * 32 + lk * 8]);
#pragma unroll
        for (int mt = 0; mt < 2; mt++)
#pragma unroll
            for (int nt = 0; nt < 4; nt++)
                acc[mt][nt] = __builtin_amdgcn_mfma_f32_16x16x32_bf16(
                    a[mt], b[nt], acc[mt][nt], 0, 0, 0);
    }

    // NCHW scatter via LDS transpose (reuse Bs as float[128][68])
    __syncthreads();
    float* T = (float*)Bs;
#pragma unroll
    for (int mt = 0; mt < 2; mt++) {
        int rloc = wm * 32 + mt * 16 + lk * 4;
#pragma unroll
        for (int nt = 0; nt < 4; nt++) {
            int col = wn * 64 + nt * 16 + lr;
#pragma unroll
            for (int r = 0; r < 4; r++)
                T[col * 68 + rloc + r] = acc[mt][nt][r];
        }
    }
    __syncthreads();
    int o = tid >> 1, half = tid & 1;
    float* op = out + (((size_t)(n * CC + o)) << 12) + hw0 + half * 32;
#pragma unroll
    for (int i = 0; i < 8; i++) {
        float4 v = *(const float4*)(&T[o * 68 + half * 32 + i * 4]);
        *(float4*)(op + i * 4) = v;
    }
}

// ---------------------------------------------------------------------------
extern "C" void kernel_launch(void* const* d_in, const int* in_sizes, int n_in,
                              void* d_out, int out_size, void* d_ws, size_t ws_size,
                              hipStream_t stream)
{
    const float* x     = (const float*)d_in[0];
    const float* Wv    = (const float*)d_in[1];
    const float* bv    = (const float*)d_in[2];
    const float* Wom   = (const float*)d_in[3];
    const float* bom   = (const float*)d_in[4];
    const float* Wo    = (const float*)d_in[5];
    const float* gamma = (const float*)d_in[6];
    const float* beta  = (const float*)d_in[7];
    const float* Wc    = (const float*)d_in[8];
    float* out = (float*)d_out;

    char* ws = (char*)d_ws;
    unsigned short* val   = (unsigned short*)ws;   ws += (size_t)NL * CC * 2;    // 4 MB
    float*          omb   = (float*)ws;            ws += (size_t)NL * OMP * 4;   // 7.34 MB
    unsigned int*   sbuf  = (unsigned int*)ws;     ws += (size_t)NL * CC * 2;    // 4 MB
    float*          ybuf  = (float*)ws;            ws += (size_t)NL * CC * 4;    // 8 MB
    unsigned short* Wcomb = (unsigned short*)ws;   ws += 240 * 128 * 2;
    unsigned short* WoT   = (unsigned short*)ws;   ws += 128 * 128 * 2;
    unsigned short* Wcb   = (unsigned short*)ws;   ws += 128 * 128 * 2;
    float*          stats = (float*)ws;            ws += 2048;
    unsigned short* xT    = (unsigned short*)ws;   ws += (size_t)NL * CC * 2;    // 4 MB

    dim3 b256(256);

    prep_kernel<<<504, b256, 0, stream>>>(Wv, Wom, Wo, Wc, x, Wcomb, WoT, Wcb, xT, stats);

    // ---- DCN block 1 ----
    gemm_vom_kernel<0><<<256, b256, 0, stream>>>(xT, Wcomb, bv, bom,
                                                 nullptr, nullptr, nullptr, val, omb);
    sample_kernel<<<1024, b256, 0, stream>>>(val, omb, sbuf);
    gemm_o_bn_kernel<<<256, b256, 0, stream>>>((const unsigned short*)sbuf, WoT, ybuf, stats);

    // ---- DCN block 2 (bn+relu fused into A-staging) ----
    gemm_vom_kernel<1><<<256, b256, 0, stream>>>(ybuf, Wcomb, bv, bom,
                                                 stats, gamma, beta, val, omb);
    sample_kernel<<<1024, b256, 0, stream>>>(val, omb, sbuf);
    gemm_o_bn_kernel<<<256, b256, 0, stream>>>((const unsigned short*)sbuf, WoT, ybuf, stats + 256);

    // ---- final: bn2 + residual + 1x1 conv, NCHW out ----
    gemm_final_kernel<<<256, b256, 0, stream>>>(ybuf, x, Wcb, stats + 256, gamma, beta, out);
}

// Round 9
// 149.498 us; speedup vs baseline: 1.0073x; 1.0073x over previous
//
#include <hip/hip_runtime.h>
#include <math.h>

// Problem constants
#define CC   128         // channels
#define NL   16384       // N * H * W = 4*64*64
#define LHW  4096        // H*W
#define OMP  112         // padded om row stride: 4 groups x (27+1 pad) floats
#define HH   64
#define WW   64

typedef __attribute__((ext_vector_type(8))) short short8;
typedef __attribute__((ext_vector_type(4))) float f32x4;

__device__ __forceinline__ unsigned short f2bf(float f) {
    union { float f; unsigned u; } v; v.f = f;
    unsigned r = v.u + 0x7fff + ((v.u >> 16) & 1);   // RNE
    return (unsigned short)(r >> 16);
}
__device__ __forceinline__ float bf2f(unsigned short u) {
    union { unsigned u; float f; } v; v.u = ((unsigned)u) << 16;
    return v.f;
}

// ---------------------------------------------------------------------------
// Weight prep + stats zero (r7-proven: 248 blocks, no xT).
// Wcomb[240][128] bf16: rows 0..127 = Wv^T, rows 128..239 = Wom^T (pad 108->112)
// WoT[128][128] = Wo^T ; Wcb[128][128] = Wc (already Bt layout: [o][c]).
// ---------------------------------------------------------------------------
__global__ __launch_bounds__(256) void prep_kernel(
    const float* __restrict__ Wv, const float* __restrict__ Wom,
    const float* __restrict__ Wo, const float* __restrict__ Wc,
    unsigned short* __restrict__ Wcomb, unsigned short* __restrict__ WoT,
    unsigned short* __restrict__ Wcb, float* __restrict__ stats)
{
    int tid = threadIdx.x;
    if (blockIdx.x == 0) {               // zero 512 stats floats
        stats[tid] = 0.0f;
        stats[256 + tid] = 0.0f;
    }
    int i = blockIdx.x * 256 + tid;      // 63488 total
    if (i < 16384) {
        int n = i >> 7, k = i & 127;
        Wcomb[i] = f2bf(Wv[k * CC + n]);
    } else if (i < 30720) {
        int j = i - 16384; int n = j >> 7, k = j & 127;   // n in 0..111
        Wcomb[16384 + j] = (n < 108) ? f2bf(Wom[k * 108 + n]) : (unsigned short)0;
    } else if (i < 47104) {
        int j = i - 30720; int n = j >> 7, k = j & 127;
        WoT[j] = f2bf(Wo[k * CC + n]);
    } else if (i < 63488) {
        int j = i - 47104;
        Wcb[j] = f2bf(Wc[j]);
    }
}

// ---------------------------------------------------------------------------
// Fused value+om GEMM: [M=16384 x N=240 x K=128].
// IN_MODE 0: A = x in NCHW (transpose in LDS staging, r7-proven).
// IN_MODE 1: A = bn_relu(ybuf) (NHWC), bn in staging; b32-packed LDS writes
//            (bit-identical LDS image, half the LDS write issues).
// Outputs:
//   val bf16 in g-major layout [n][g][hw][32] (+bv)
//   omb fp32 in layout [nl][4][28] (+bom, e<27)
// 4 waves; wave w computes rows w*16..w*16+15 x all 240 cols (15 frags).
// ---------------------------------------------------------------------------
template<int IN_MODE>
__global__ __launch_bounds__(256) void gemm_vom_kernel(
    const float* __restrict__ Ain, const unsigned short* __restrict__ Wcomb,
    const float* __restrict__ bv, const float* __restrict__ bom,
    const float* __restrict__ stats, const float* __restrict__ gamma,
    const float* __restrict__ beta,
    unsigned short* __restrict__ val, float* __restrict__ omb)
{
    __shared__ unsigned short As[64 * 136];
    __shared__ unsigned short Bs[240 * 136];
    __shared__ float bnsc[128], bnsh[128];

    int tid = threadIdx.x;
    int block_m = blockIdx.x * 64;

    if (IN_MODE == 1 && tid < 128) {
        const float inv = 1.0f / 16384.0f;
        float mean = stats[tid] * inv;
        float var  = stats[128 + tid] * inv - mean * mean;
        float sc   = rsqrtf(var + 1e-5f) * gamma[tid];
        bnsc[tid] = sc;
        bnsh[tid] = beta[tid] - mean * sc;
    }

    // stage B: 240 rows x 128 bf16 = 3840 chunks of 8  (15 x 256, exact)
#pragma unroll
    for (int i = 0; i < 15; i++) {
        int id = tid + i * 256;
        int r = id >> 4, kc = id & 15;
        float4 v = *(const float4*)(Wcomb + (size_t)r * CC + kc * 8);
        *(float4*)(&Bs[r * 136 + kc * 8]) = v;
    }

    if (IN_MODE == 0) {
        // A from x NCHW: 128 channels x 16 float4 along hw
        int n   = block_m >> 12;
        int hw0 = block_m & 4095;
#pragma unroll
        for (int i = 0; i < 8; i++) {
            int id = tid + i * 256;          // 0..2047
            int c  = id >> 4, j4 = id & 15;
            float4 v = *(const float4*)(Ain + (((size_t)(n * CC + c)) << 12) + hw0 + j4 * 4);
            As[(j4 * 4 + 0) * 136 + c] = f2bf(v.x);
            As[(j4 * 4 + 1) * 136 + c] = f2bf(v.y);
            As[(j4 * 4 + 2) * 136 + c] = f2bf(v.z);
            As[(j4 * 4 + 3) * 136 + c] = f2bf(v.w);
        }
    } else {
        __syncthreads();                     // bnsc/bnsh ready
#pragma unroll
        for (int i = 0; i < 8; i++) {
            int id = tid + i * 256;          // 0..2047
            int r  = id >> 5, c4 = id & 31;
            float4 v = *(const float4*)(Ain + (size_t)(block_m + r) * CC + c4 * 4);
            int c = c4 * 4;
            float a0 = fmaxf(v.x * bnsc[c + 0] + bnsh[c + 0], 0.0f);
            float a1 = fmaxf(v.y * bnsc[c + 1] + bnsh[c + 1], 0.0f);
            float a2 = fmaxf(v.z * bnsc[c + 2] + bnsh[c + 2], 0.0f);
            float a3 = fmaxf(v.w * bnsc[c + 3] + bnsh[c + 3], 0.0f);
            unsigned p0 = (unsigned)f2bf(a0) | ((unsigned)f2bf(a1) << 16);
            unsigned p1 = (unsigned)f2bf(a2) | ((unsigned)f2bf(a3) << 16);
            *(unsigned*)(&As[r * 136 + c])     = p0;   // (136r+c)*2 % 4 == 0
            *(unsigned*)(&As[r * 136 + c + 2]) = p1;
        }
    }
    __syncthreads();

    int w  = tid >> 6;
    int l  = tid & 63;
    int lr = l & 15, lk = l >> 4;

    f32x4 acc[15];
#pragma unroll
    for (int nt = 0; nt < 15; nt++) acc[nt] = (f32x4){0.f, 0.f, 0.f, 0.f};

#pragma unroll
    for (int kk = 0; kk < 4; kk++) {
        short8 a = *(const short8*)(&As[(w * 16 + lr) * 136 + kk * 32 + lk * 8]);
#pragma unroll
        for (int nt = 0; nt < 15; nt++) {
            short8 b = *(const short8*)(&Bs[(nt * 16 + lr) * 136 + kk * 32 + lk * 8]);
            acc[nt] = __builtin_amdgcn_mfma_f32_16x16x32_bf16(a, b, acc[nt], 0, 0, 0);
        }
    }

    int row0  = block_m + w * 16 + lk * 4;
    int nimg  = block_m >> 12;               // constant per block (4096 % 64 == 0)
    int hwrow = row0 & 4095;
#pragma unroll
    for (int nt = 0; nt < 8; nt++) {
        int col = nt * 16 + lr;
        float bb = bv[col];
        int gg = col >> 5, ch = col & 31;
        unsigned short* vp = val + (((size_t)(nimg * 4 + gg)) << 17) + (size_t)hwrow * 32 + ch;
#pragma unroll
        for (int r = 0; r < 4; r++)
            vp[r * 32] = f2bf(acc[nt][r] + bb);
    }
#pragma unroll
    for (int nt = 8; nt < 15; nt++) {
        int col = (nt - 8) * 16 + lr;        // 0..111
        if (col < 108) {
            int gg = col / 27, e = col - gg * 27;
            float bb = bom[col];
#pragma unroll
            for (int r = 0; r < 4; r++)
                omb[(size_t)(row0 + r) * OMP + gg * 28 + e] = acc[nt][r] + bb;
        }
    }
}

// ---------------------------------------------------------------------------
// Deformable sampling: 4 lanes x 8 ch per (nl,g) unit.
// val in g-major layout: pixel g-slice = 64B contiguous; corner pair
// (x0,x0+1) = one 128B line. om loaded as 7 x float4 (16B-aligned 28-slice).
// Per-channel accumulation chains bit-identical to the verified baseline.
// ---------------------------------------------------------------------------
__global__ __launch_bounds__(256) void sample_kernel(
    const unsigned short* __restrict__ val, const float* __restrict__ omb,
    unsigned int* __restrict__ sbuf)
{
    int tid   = threadIdx.x;
    int gid   = blockIdx.x * 256 + tid;
    int unit  = gid >> 2;                    // 65536 units
    int lane4 = gid & 3;
    int nl = unit >> 2;
    int g  = unit & 3;
    int n  = nl >> 12;
    int hw = nl & 4095;
    int h  = hw >> 6;
    int w  = hw & 63;

    const float* omp = omb + (size_t)nl * OMP + g * 28;   // 16B aligned
    f32x4 o4[7];
#pragma unroll
    for (int i = 0; i < 7; i++) o4[i] = *(const f32x4*)(omp + i * 4);

    const unsigned short* vb = val + (((size_t)(n * 4 + g)) << 17) + lane4 * 8;

    float acc0 = 0.0f, acc1 = 0.0f, acc2 = 0.0f, acc3 = 0.0f;
    float acc4 = 0.0f, acc5 = 0.0f, acc6 = 0.0f, acc7 = 0.0f;
#pragma unroll
    for (int k = 0; k < 9; k++) {
        float ox = o4[(2 * k) >> 2][(2 * k) & 3];
        float oy = o4[(2 * k + 1) >> 2][(2 * k + 1) & 3];
        float mk = o4[(18 + k) >> 2][(18 + k) & 3];
        float ly = (float)(h + k / 3 - 1) + oy;
        float lx = (float)(w + k % 3 - 1) + ox;
        float y0f = floorf(ly), x0f = floorf(lx);
        float wy = ly - y0f, wx = lx - x0f;
        int y0 = (int)y0f, x0 = (int)x0f;

        float v0 = 0.0f, v1 = 0.0f, v2 = 0.0f, v3 = 0.0f;
        float v4 = 0.0f, v5 = 0.0f, v6 = 0.0f, v7 = 0.0f;
#pragma unroll
        for (int cy = 0; cy < 2; cy++) {
#pragma unroll
            for (int cx = 0; cx < 2; cx++) {
                int yi = y0 + cy, xi = x0 + cx;
                float wgt = (cy ? wy : 1.0f - wy) * (cx ? wx : 1.0f - wx);
                bool valid = (yi >= 0) && (yi < HH) && (xi >= 0) && (xi < WW);
                wgt = valid ? wgt : 0.0f;
                int yc = min(max(yi, 0), HH - 1);
                int xc = min(max(xi, 0), WW - 1);
                uint4 pv = *(const uint4*)(vb + (size_t)(yc * WW + xc) * 32);
                v0 += bf2f((unsigned short)(pv.x & 0xffff)) * wgt;
                v1 += bf2f((unsigned short)(pv.x >> 16)) * wgt;
                v2 += bf2f((unsigned short)(pv.y & 0xffff)) * wgt;
                v3 += bf2f((unsigned short)(pv.y >> 16)) * wgt;
                v4 += bf2f((unsigned short)(pv.z & 0xffff)) * wgt;
                v5 += bf2f((unsigned short)(pv.z >> 16)) * wgt;
                v6 += bf2f((unsigned short)(pv.w & 0xffff)) * wgt;
                v7 += bf2f((unsigned short)(pv.w >> 16)) * wgt;
            }
        }
        acc0 += mk * v0;
        acc1 += mk * v1;
        acc2 += mk * v2;
        acc3 += mk * v3;
        acc4 += mk * v4;
        acc5 += mk * v5;
        acc6 += mk * v6;
        acc7 += mk * v7;
    }
    uint4 packed;
    packed.x = (unsigned int)f2bf(acc0) | ((unsigned int)f2bf(acc1) << 16);
    packed.y = (unsigned int)f2bf(acc2) | ((unsigned int)f2bf(acc3) << 16);
    packed.z = (unsigned int)f2bf(acc4) | ((unsigned int)f2bf(acc5) << 16);
    packed.w = (unsigned int)f2bf(acc6) | ((unsigned int)f2bf(acc7) << 16);
    *(uint4*)(&sbuf[(size_t)nl * 64 + g * 16 + lane4 * 4]) = packed;
}

// ---------------------------------------------------------------------------
// Wo GEMM + fused BN-stats: ybuf = sbuf @ Wo ; stats[c] += sum, stats[128+c] += sumsq
// 2x2 wave grid, 64-row tile.
// ---------------------------------------------------------------------------
__global__ __launch_bounds__(256) void gemm_o_bn_kernel(
    const unsigned short* __restrict__ A, const unsigned short* __restrict__ Bt,
    float* __restrict__ ybuf, float* __restrict__ stats)
{
    __shared__ unsigned short As[64 * 136];
    __shared__ unsigned short Bs[128 * 136];
    __shared__ float lstat[256];

    int tid = threadIdx.x;
    int block_m = blockIdx.x * 64;
    lstat[tid] = 0.0f;

#pragma unroll
    for (int i = 0; i < 4; i++) {
        int id = tid + i * 256;
        int r = id >> 4, kc = id & 15;
        float4 v = *(const float4*)(A + (size_t)(block_m + r) * CC + kc * 8);
        *(float4*)(&As[r * 136 + kc * 8]) = v;
    }
#pragma unroll
    for (int i = 0; i < 8; i++) {
        int id = tid + i * 256;
        int r = id >> 4, kc = id & 15;
        float4 v = *(const float4*)(Bt + (size_t)r * CC + kc * 8);
        *(float4*)(&Bs[r * 136 + kc * 8]) = v;
    }
    __syncthreads();

    int w  = tid >> 6;
    int l  = tid & 63;
    int wm = w & 1, wn = w >> 1;
    int lr = l & 15, lk = l >> 4;

    f32x4 acc[2][4];
#pragma unroll
    for (int mt = 0; mt < 2; mt++)
#pragma unroll
        for (int nt = 0; nt < 4; nt++) acc[mt][nt] = (f32x4){0.f, 0.f, 0.f, 0.f};

#pragma unroll
    for (int kk = 0; kk < 4; kk++) {
        short8 a[2], b[4];
#pragma unroll
        for (int mt = 0; mt < 2; mt++)
            a[mt] = *(const short8*)(&As[(wm * 32 + mt * 16 + lr) * 136 + kk * 32 + lk * 8]);
#pragma unroll
        for (int nt = 0; nt < 4; nt++)
            b[nt] = *(const short8*)(&Bs[(wn * 64 + nt * 16 + lr) * 136 + kk * 32 + lk * 8]);
#pragma unroll
        for (int mt = 0; mt < 2; mt++)
#pragma unroll
            for (int nt = 0; nt < 4; nt++)
                acc[mt][nt] = __builtin_amdgcn_mfma_f32_16x16x32_bf16(
                    a[mt], b[nt], acc[mt][nt], 0, 0, 0);
    }

    // write + per-lane stats
#pragma unroll
    for (int nt = 0; nt < 4; nt++) {
        int col = wn * 64 + nt * 16 + lr;
        float s = 0.0f, sq = 0.0f;
#pragma unroll
        for (int mt = 0; mt < 2; mt++) {
            int row0 = block_m + wm * 32 + mt * 16 + lk * 4;
#pragma unroll
            for (int r = 0; r < 4; r++) {
                float v = acc[mt][nt][r];
                ybuf[(size_t)(row0 + r) * CC + col] = v;
                s += v;
                sq += v * v;
            }
        }
        atomicAdd(&lstat[col], s);
        atomicAdd(&lstat[128 + col], sq);
    }
    __syncthreads();
    if (tid < 128) {
        atomicAdd(&stats[tid], lstat[tid]);
        atomicAdd(&stats[128 + tid], lstat[128 + tid]);
    }
}

// ---------------------------------------------------------------------------
// Final GEMM: A = bn(ybuf) + x_residual(NCHW), B = Wc; out NCHW fp32.
// b32-packed LDS writes in A-staging (bit-identical image).
// ---------------------------------------------------------------------------
__global__ __launch_bounds__(256) void gemm_final_kernel(
    const float* __restrict__ ybuf, const float* __restrict__ x,
    const unsigned short* __restrict__ Bt, const float* __restrict__ stats,
    const float* __restrict__ gamma, const float* __restrict__ beta,
    float* __restrict__ out)
{
    __shared__ unsigned short As[64 * 136];
    __shared__ unsigned short Bs[128 * 136];
    __shared__ float Xs[64 * 132];
    __shared__ float bnsc[128], bnsh[128];

    int tid = threadIdx.x;
    int block_m = blockIdx.x * 64;
    int n   = block_m >> 12;
    int hw0 = block_m & 4095;

    if (tid < 128) {
        const float inv = 1.0f / 16384.0f;
        float mean = stats[tid] * inv;
        float var  = stats[128 + tid] * inv - mean * mean;
        float sc   = rsqrtf(var + 1e-5f) * gamma[tid];
        bnsc[tid] = sc;
        bnsh[tid] = beta[tid] - mean * sc;
    }

    // stage x residual (NCHW -> LDS transpose, fp32)
#pragma unroll
    for (int i = 0; i < 8; i++) {
        int id = tid + i * 256;
        int c  = id >> 4, j4 = id & 15;
        float4 v = *(const float4*)(x + (((size_t)(n * CC + c)) << 12) + hw0 + j4 * 4);
        Xs[(j4 * 4 + 0) * 132 + c] = v.x;
        Xs[(j4 * 4 + 1) * 132 + c] = v.y;
        Xs[(j4 * 4 + 2) * 132 + c] = v.z;
        Xs[(j4 * 4 + 3) * 132 + c] = v.w;
    }
    // stage B
#pragma unroll
    for (int i = 0; i < 8; i++) {
        int id = tid + i * 256;
        int r = id >> 4, kc = id & 15;
        float4 v = *(const float4*)(Bt + (size_t)r * CC + kc * 8);
        *(float4*)(&Bs[r * 136 + kc * 8]) = v;
    }
    __syncthreads();

    // stage A = bn(ybuf) + Xs   (b32-packed LDS writes, bit-identical image)
#pragma unroll
    for (int i = 0; i < 8; i++) {
        int id = tid + i * 256;
        int r  = id >> 5, c4 = id & 31;
        float4 v = *(const float4*)(ybuf + (size_t)(block_m + r) * CC + c4 * 4);
        int c = c4 * 4;
        float a0 = v.x * bnsc[c + 0] + bnsh[c + 0] + Xs[r * 132 + c + 0];
        float a1 = v.y * bnsc[c + 1] + bnsh[c + 1] + Xs[r * 132 + c + 1];
        float a2 = v.z * bnsc[c + 2] + bnsh[c + 2] + Xs[r * 132 + c + 2];
        float a3 = v.w * bnsc[c + 3] + bnsh[c + 3] + Xs[r * 132 + c + 3];
        unsigned p0 = (unsigned)f2bf(a0) | ((unsigned)f2bf(a1) << 16);
        unsigned p1 = (unsigned)f2bf(a2) | ((unsigned)f2bf(a3) << 16);
        *(unsigned*)(&As[r * 136 + c])     = p0;
        *(unsigned*)(&As[r * 136 + c + 2]) = p1;
    }
    __syncthreads();

    int w  = tid >> 6;
    int l  = tid & 63;
    int wm = w & 1, wn = w >> 1;
    int lr = l & 15, lk = l >> 4;

    f32x4 acc[2][4];
#pragma unroll
    for (int mt = 0; mt < 2; mt++)
#pragma unroll
        for (int nt = 0; nt < 4; nt++) acc[mt][nt] = (f32x4){0.f, 0.f, 0.f, 0.f};

#pragma unroll
    for (int kk = 0; kk < 4; kk++) {
        short8 a[2], b[4];
#pragma unroll
        for (int mt = 0; mt < 2; mt++)
            a[mt] = *(const short8*)(&As[(wm * 32 + mt * 16 + lr) * 136 + kk * 32 + lk * 8]);
#pragma unroll
        for (int nt = 0; nt < 4; nt++)
            b[nt] = *(const short8*)(&Bs[(wn * 64 + nt * 16 + lr) * 136 + kk * 32 + lk * 8]);
#pragma unroll
        for (int mt = 0; mt < 2; mt++)
#pragma unroll
            for (int nt = 0; nt < 4; nt++)
                acc[mt][nt] = __builtin_amdgcn_mfma_f32_16x16x32_bf16(
                    a[mt], b[nt], acc[mt][nt], 0, 0, 0);
    }

    // NCHW scatter via LDS transpose (reuse Bs as float[128][68])
    __syncthreads();
    float* T = (float*)Bs;
#pragma unroll
    for (int mt = 0; mt < 2; mt++) {
        int rloc = wm * 32 + mt * 16 + lk * 4;
#pragma unroll
        for (int nt = 0; nt < 4; nt++) {
            int col = wn * 64 + nt * 16 + lr;
#pragma unroll
            for (int r = 0; r < 4; r++)
                T[col * 68 + rloc + r] = acc[mt][nt][r];
        }
    }
    __syncthreads();
    int o = tid >> 1, half = tid & 1;
    float* op = out + (((size_t)(n * CC + o)) << 12) + hw0 + half * 32;
#pragma unroll
    for (int i = 0; i < 8; i++) {
        float4 v = *(const float4*)(&T[o * 68 + half * 32 + i * 4]);
        *(float4*)(op + i * 4) = v;
    }
}

// ---------------------------------------------------------------------------
extern "C" void kernel_launch(void* const* d_in, const int* in_sizes, int n_in,
                              void* d_out, int out_size, void* d_ws, size_t ws_size,
                              hipStream_t stream)
{
    const float* x     = (const float*)d_in[0];
    const float* Wv    = (const float*)d_in[1];
    const float* bv    = (const float*)d_in[2];
    const float* Wom   = (const float*)d_in[3];
    const float* bom   = (const float*)d_in[4];
    const float* Wo    = (const float*)d_in[5];
    const float* gamma = (const float*)d_in[6];
    const float* beta  = (const float*)d_in[7];
    const float* Wc    = (const float*)d_in[8];
    float* out = (float*)d_out;

    char* ws = (char*)d_ws;
    unsigned short* val   = (unsigned short*)ws;   ws += (size_t)NL * CC * 2;    // 4 MB
    float*          omb   = (float*)ws;            ws += (size_t)NL * OMP * 4;   // 7.34 MB
    unsigned int*   sbuf  = (unsigned int*)ws;     ws += (size_t)NL * CC * 2;    // 4 MB
    float*          ybuf  = (float*)ws;            ws += (size_t)NL * CC * 4;    // 8 MB
    unsigned short* Wcomb = (unsigned short*)ws;   ws += 240 * 128 * 2;
    unsigned short* WoT   = (unsigned short*)ws;   ws += 128 * 128 * 2;
    unsigned short* Wcb   = (unsigned short*)ws;   ws += 128 * 128 * 2;
    float*          stats = (float*)ws;            ws += 2048;

    dim3 b256(256);

    prep_kernel<<<248, b256, 0, stream>>>(Wv, Wom, Wo, Wc, Wcomb, WoT, Wcb, stats);

    // ---- DCN block 1 ----
    gemm_vom_kernel<0><<<256, b256, 0, stream>>>(x, Wcomb, bv, bom,
                                                 nullptr, nullptr, nullptr, val, omb);
    sample_kernel<<<1024, b256, 0, stream>>>(val, omb, sbuf);
    gemm_o_bn_kernel<<<256, b256, 0, stream>>>((const unsigned short*)sbuf, WoT, ybuf, stats);

    // ---- DCN block 2 (bn+relu fused into A-staging) ----
    gemm_vom_kernel<1><<<256, b256, 0, stream>>>(ybuf, Wcomb, bv, bom,
                                                 stats, gamma, beta, val, omb);
    sample_kernel<<<1024, b256, 0, stream>>>(val, omb, sbuf);
    gemm_o_bn_kernel<<<256, b256, 0, stream>>>((const unsigned short*)sbuf, WoT, ybuf, stats + 256);

    // ---- final: bn2 + residual + 1x1 conv, NCHW out ----
    gemm_final_kernel<<<256, b256, 0, stream>>>(ybuf, x, Wcb, stats + 256, gamma, beta, out);
}